// Round 18
// baseline (60.049 us; speedup 1.0000x reference)
//
#include <hip/hip_runtime.h>
#include <hip/hip_bf16.h>
#include <math.h>

#define NCLS 151
#define NQ   100
#define NB   2
#define HW   16384   // 128*128
#define NCO  150     // classes after dropping class 0
#define OUTW 512
#define KPAD 128     // Q padded to 128
#define CPAD 160     // C padded to 160
#define CBLK 32      // classes per c-split (5 splits, looped in-kernel)
#define AROW 136     // s_a row stride in ushort
#define BROW 136     // s_bt row stride in ushort
#define SROW 130     // s_seg row stride in float

using short8  = __attribute__((ext_vector_type(8))) short;
using short4v = __attribute__((ext_vector_type(4))) short;
using f32x4   = __attribute__((ext_vector_type(4))) float;

static __device__ __forceinline__ ushort f2bf(float x) {
    union { float f; unsigned u; } v; v.f = x;
    unsigned r = v.u + 0x7fff + ((v.u >> 16) & 1);   // RNE
    return (ushort)(r >> 16);
}

// ---------------- Single mega-kernel: softmax + sigmoid + MFMA einsum + resize --------
// ONE block per CU: grid (128 r-pairs, 2 batches) = 256 blocks, 1024 thr (16 waves).
// T14 async-STAGE prelude: issue all mask loads -> regs, softmax while in flight,
// then sigmoid/pack -> s_bt. Precise pad-zeroing -> single prelude barrier.
__global__ __launch_bounds__(1024, 1) void fused_k(const float* __restrict__ logits,
                                                   const float* __restrict__ masks,
                                                   float* __restrict__ out) {
    __shared__ __align__(16) ushort s_a[CPAD][AROW];     // 43,520 B
    __shared__ __align__(16) ushort s_bt[256][BROW];     // 69,632 B
    __shared__ float s_seg[2][CBLK][SROW];               // 33,280 B

    int r   = blockIdx.x;
    int b   = blockIdx.y;
    int tid = threadIdx.x;
    int r1  = min(r + 1, 127);
    int wid = tid >> 6, lane = tid & 63;
    int pr = lane & 15, kg = lane >> 4;

    // ---- (1) issue ALL mask loads into registers (in flight during softmax) ----
    float xv[8][4];
    {
        const float* mb = masks + (size_t)b * NQ * HW;
        #pragma unroll
        for (int j = 0; j < 8; ++j) {
            int i = j * 1024 + tid;
            int p = i & 255, kk4 = i >> 8;
            int gpix = ((p < 128) ? r : r1) * 128 + (p & 127);
            #pragma unroll
            for (int e = 0; e < 4; ++e) {
                int gk = kk4 * 4 + e;
                xv[j][e] = (gk < NQ)
                    ? __builtin_nontemporal_load(&mb[(size_t)gk * HW + gpix]) : 0.f;
            }
        }
    }

    // ---- (2) precise pad-zeroing (no overlap with softmax writes) ----
    // q-pad cols 100..127 for class rows 0..149
    for (int i = tid; i < 150 * 14; i += 1024) {
        int row = i / 14, cu = i % 14;
        *(unsigned*)&s_a[row][100 + cu * 2] = 0u;
    }
    // c-pad rows 150..159, cols 0..127
    for (int i = tid; i < 10 * 64; i += 1024) {
        int row = 150 + (i >> 6), cu = i & 63;
        *(unsigned*)&s_a[row][cu * 2] = 0u;
    }

    // ---- (3) in-block softmax -> s_a[c-1][q] (8-lane groups; overlaps mask loads) ----
    {
        int grp = lane >> 3, e = lane & 7;
        int q = wid * 8 + grp;                 // 0..127, active < 100
        if (q < NQ) {
            const float* in = logits + (size_t)(b * NQ + q) * NCLS;
            float v[19];
            float m = -1e30f;
            #pragma unroll
            for (int i = 0; i < 19; ++i) {
                int c = e + 8 * i;
                v[i] = (c < NCLS) ? in[c] : -1e30f;
                m = fmaxf(m, v[i]);
            }
            m = fmaxf(m, __shfl_xor(m, 1));
            m = fmaxf(m, __shfl_xor(m, 2));
            m = fmaxf(m, __shfl_xor(m, 4));
            float s = 0.f;
            #pragma unroll
            for (int i = 0; i < 19; ++i) { v[i] = __expf(v[i] - m); s += v[i]; }
            s += __shfl_xor(s, 1);
            s += __shfl_xor(s, 2);
            s += __shfl_xor(s, 4);
            float inv = 1.f / s;
            #pragma unroll
            for (int i = 0; i < 19; ++i) {
                int c = e + 8 * i;
                if (c >= 1 && c < NCLS) s_a[c - 1][q] = f2bf(v[i] * inv);
            }
        }
    }

    // ---- (4) sigmoid + pack + s_bt writes (loads have landed by now) ----
    #pragma unroll
    for (int j = 0; j < 8; ++j) {
        int i = j * 1024 + tid;
        int p = i & 255, kk4 = i >> 8;
        short4v sv;
        #pragma unroll
        for (int e = 0; e < 4; ++e) {
            int gk = kk4 * 4 + e;
            float s = (gk < NQ) ? 1.f / (1.f + __expf(-xv[j][e])) : 0.f;
            sv[e] = (short)f2bf(s);
        }
        *(short4v*)&s_bt[p][kk4 * 4] = sv;
    }
    __syncthreads();   // single prelude barrier: s_a (zeros+softmax) + s_bt visible

    // ---- (5) loop over 5 c-splits: MFMA -> s_seg -> emission ----
    int pw = wid * 16;            // wave's 16-px n-tile
    for (int cs = 0; cs < 5; ++cs) {
        f32x4 acc[2];
        acc[0] = (f32x4){0.f, 0.f, 0.f, 0.f};
        acc[1] = (f32x4){0.f, 0.f, 0.f, 0.f};

        #pragma unroll
        for (int ks = 0; ks < 4; ++ks) {
            short8 bf = *(const short8*)&s_bt[pw + pr][ks * 32 + kg * 8];
            #pragma unroll
            for (int ct = 0; ct < 2; ++ct) {
                short8 af = *(const short8*)&s_a[cs * CBLK + ct * 16 + pr][ks * 32 + kg * 8];
                acc[ct] = __builtin_amdgcn_mfma_f32_16x16x32_bf16(af, bf, acc[ct], 0, 0, 0);
            }
        }

        __syncthreads();   // previous cs emission reads of s_seg complete

        // ---- acc -> s_seg (D layout: c-local = ct*16 + kg*4 + j, px = pw + pr) ----
        {
            int p = pw + pr, rs = p >> 7, px = p & 127;
            #pragma unroll
            for (int ct = 0; ct < 2; ++ct)
                #pragma unroll
                for (int j = 0; j < 4; ++j)
                    s_seg[rs][ct * 16 + kg * 4 + j][px] = acc[ct][j];
        }
        __syncthreads();

        // ---- emission: w-lerps once per (c,k), normal float4 stores ----
        int cbase = cs * CBLK;
        for (int it = tid; it < CBLK * 128; it += 1024) {
            int k = it & 127;
            int c = it >> 7;                  // wave-uniform
            int cg = cbase + c;
            if (cg >= NCO) break;             // wave-uniform (only cs=4 trims)
            int km = max(k - 1, 0), kp = min(k + 1, 127);
            const float* s0 = s_seg[0][c];
            const float* s1 = s_seg[1][c];
            float a0 = s0[km], a1 = s0[k], a2 = s0[kp];
            float b0 = s1[km], b1 = s1[k], b2 = s1[kp];

            float t0 = a0 + 0.625f * (a1 - a0);
            float t1 = a0 + 0.875f * (a1 - a0);
            float t2 = a1 + 0.125f * (a2 - a1);
            float t3 = a1 + 0.375f * (a2 - a1);
            float u0 = b0 + 0.625f * (b1 - b0);
            float u1 = b0 + 0.875f * (b1 - b0);
            float u2 = b1 + 0.125f * (b2 - b1);
            float u3 = b1 + 0.375f * (b2 - b1);

            float* op = out + (size_t)(b * NCO + cg) * (OUTW * OUTW) + 4 * k;

            if (r == 0) {                     // rows 0,1: clamped -> pure w-lerp
                f32x4 o = {t0, t1, t2, t3};
                *(f32x4*)(op) = o;
                *(f32x4*)(op + OUTW) = o;
            }
            int nr = (r == 127) ? 2 : 4;
            #pragma unroll
            for (int ri = 0; ri < 4; ++ri) {
                if (ri >= nr) break;          // wave-uniform
                float fh = 0.125f + 0.25f * (float)ri;
                int h = 4 * r + 2 + ri;
                f32x4 o;
                o.x = t0 + fh * (u0 - t0);
                o.y = t1 + fh * (u1 - t1);
                o.z = t2 + fh * (u2 - t2);
                o.w = t3 + fh * (u3 - t3);
                *(f32x4*)(op + (size_t)h * OUTW) = o;
            }
        }
    }
}

extern "C" void kernel_launch(void* const* d_in, const int* in_sizes, int n_in,
                              void* d_out, int out_size, void* d_ws, size_t ws_size,
                              hipStream_t stream) {
    const float* logits = (const float*)d_in[0];
    const float* masks  = (const float*)d_in[1];
    float* out = (float*)d_out;

    fused_k<<<dim3(128, NB), dim3(1024), 0, stream>>>(logits, masks, out);
}

// Round 19
// 58.312 us; speedup vs baseline: 1.0298x; 1.0298x over previous
//
#include <hip/hip_runtime.h>
#include <hip/hip_bf16.h>
#include <math.h>

#define NCLS 151
#define NQ   100
#define NB   2
#define HW   16384   // 128*128
#define NCO  150     // classes after dropping class 0
#define OUTW 512
#define KPAD 128     // Q padded to 128
#define CPAD 160     // C padded to 160
#define CBLK 32      // classes per c-split (5 splits, looped in-kernel)
#define AROW 136     // s_a row stride in ushort
#define BROW 136     // s_bt row stride in ushort
#define SROW 130     // s_seg row stride in float

using short8  = __attribute__((ext_vector_type(8))) short;
using short4v = __attribute__((ext_vector_type(4))) short;
using f32x4   = __attribute__((ext_vector_type(4))) float;

static __device__ __forceinline__ ushort f2bf(float x) {
    union { float f; unsigned u; } v; v.f = x;
    unsigned r = v.u + 0x7fff + ((v.u >> 16) & 1);   // RNE
    return (ushort)(r >> 16);
}

// ---------------- Single mega-kernel: softmax + sigmoid + MFMA einsum + resize --------
// ONE block per CU: grid (128 r-pairs, 2 batches) = 256 blocks, 1024 thr (16 waves).
// XCD swizzle: adjacent r on same XCD -> shared mask row r+1 hits L2 (T1).
__global__ __launch_bounds__(1024, 1) void fused_k(const float* __restrict__ logits,
                                                   const float* __restrict__ masks,
                                                   float* __restrict__ out) {
    __shared__ __align__(16) ushort s_a[CPAD][AROW];     // 43,520 B
    __shared__ __align__(16) ushort s_bt[256][BROW];     // 69,632 B
    __shared__ float s_seg[2][CBLK][SROW];               // 33,280 B

    // bijective XCD swizzle over 128 r-blocks: dispatch round-robins x%8 across
    // XCDs; map each XCD's 16 slots to a CONTIGUOUS r-range for L2 row sharing.
    int xr  = blockIdx.x;
    int r   = (xr & 7) * 16 + (xr >> 3);
    int b   = blockIdx.y;
    int tid = threadIdx.x;
    int r1  = min(r + 1, 127);
    int wid = tid >> 6, lane = tid & 63;
    int pr = lane & 15, kg = lane >> 4;

    // ---- (1) zero s_a (covers q-pad 100..127 and c-pad 150..159) ----
    {
        float4 z = {0.f, 0.f, 0.f, 0.f};
        for (int i = tid; i < CPAD * 17; i += 1024)      // 17 float4 per 136-ushort row
            *(float4*)&s_a[i / 17][(i % 17) * 8] = z;
    }

    // ---- (2) stage B^T with in-kernel sigmoid: 256 px x 128 k (NT mask loads) ----
    {
        const float* mb = masks + (size_t)b * NQ * HW;
        #pragma unroll
        for (int i0 = 0; i0 < 8192; i0 += 1024) {
            int i = i0 + tid;
            int p = i & 255, kk4 = i >> 8;
            int gpix = ((p < 128) ? r : r1) * 128 + (p & 127);
            short4v sv;
            #pragma unroll
            for (int e = 0; e < 4; ++e) {
                int gk = kk4 * 4 + e;
                float s = 0.f;
                if (gk < NQ) {
                    float x = __builtin_nontemporal_load(&mb[(size_t)gk * HW + gpix]);
                    s = 1.f / (1.f + __expf(-x));
                }
                sv[e] = (short)f2bf(s);
            }
            *(short4v*)&s_bt[p][kk4 * 4] = sv;
        }
    }
    __syncthreads();   // s_a zeros + s_bt visible

    // ---- (3) in-block softmax -> s_a[c-1][q] (8-lane groups, one q-row each) ----
    {
        int grp = lane >> 3, e = lane & 7;
        int q = wid * 8 + grp;                 // 0..127, active < 100
        if (q < NQ) {
            const float* in = logits + (size_t)(b * NQ + q) * NCLS;
            float v[19];
            float m = -1e30f;
            #pragma unroll
            for (int i = 0; i < 19; ++i) {
                int c = e + 8 * i;
                v[i] = (c < NCLS) ? in[c] : -1e30f;
                m = fmaxf(m, v[i]);
            }
            m = fmaxf(m, __shfl_xor(m, 1));
            m = fmaxf(m, __shfl_xor(m, 2));
            m = fmaxf(m, __shfl_xor(m, 4));
            float s = 0.f;
            #pragma unroll
            for (int i = 0; i < 19; ++i) { v[i] = __expf(v[i] - m); s += v[i]; }
            s += __shfl_xor(s, 1);
            s += __shfl_xor(s, 2);
            s += __shfl_xor(s, 4);
            float inv = 1.f / s;
            #pragma unroll
            for (int i = 0; i < 19; ++i) {
                int c = e + 8 * i;
                if (c >= 1 && c < NCLS) s_a[c - 1][q] = f2bf(v[i] * inv);
            }
        }
    }
    __syncthreads();   // s_a ready

    // ---- (4) loop over 5 c-splits: MFMA -> s_seg -> emission ----
    int pw = wid * 16;            // wave's 16-px n-tile
    for (int cs = 0; cs < 5; ++cs) {
        f32x4 acc[2];
        acc[0] = (f32x4){0.f, 0.f, 0.f, 0.f};
        acc[1] = (f32x4){0.f, 0.f, 0.f, 0.f};

        #pragma unroll
        for (int ks = 0; ks < 4; ++ks) {
            short8 bf = *(const short8*)&s_bt[pw + pr][ks * 32 + kg * 8];
            #pragma unroll
            for (int ct = 0; ct < 2; ++ct) {
                short8 af = *(const short8*)&s_a[cs * CBLK + ct * 16 + pr][ks * 32 + kg * 8];
                acc[ct] = __builtin_amdgcn_mfma_f32_16x16x32_bf16(af, bf, acc[ct], 0, 0, 0);
            }
        }

        __syncthreads();   // previous cs emission reads of s_seg complete

        // ---- acc -> s_seg (D layout: c-local = ct*16 + kg*4 + j, px = pw + pr) ----
        {
            int p = pw + pr, rs = p >> 7, px = p & 127;
            #pragma unroll
            for (int ct = 0; ct < 2; ++ct)
                #pragma unroll
                for (int j = 0; j < 4; ++j)
                    s_seg[rs][ct * 16 + kg * 4 + j][px] = acc[ct][j];
        }
        __syncthreads();

        // ---- emission: w-lerps once per (c,k), normal float4 stores ----
        int cbase = cs * CBLK;
        for (int it = tid; it < CBLK * 128; it += 1024) {
            int k = it & 127;
            int c = it >> 7;                  // wave-uniform
            int cg = cbase + c;
            if (cg >= NCO) break;             // wave-uniform (only cs=4 trims)
            int km = max(k - 1, 0), kp = min(k + 1, 127);
            const float* s0 = s_seg[0][c];
            const float* s1 = s_seg[1][c];
            float a0 = s0[km], a1 = s0[k], a2 = s0[kp];
            float b0 = s1[km], b1 = s1[k], b2 = s1[kp];

            float t0 = a0 + 0.625f * (a1 - a0);
            float t1 = a0 + 0.875f * (a1 - a0);
            float t2 = a1 + 0.125f * (a2 - a1);
            float t3 = a1 + 0.375f * (a2 - a1);
            float u0 = b0 + 0.625f * (b1 - b0);
            float u1 = b0 + 0.875f * (b1 - b0);
            float u2 = b1 + 0.125f * (b2 - b1);
            float u3 = b1 + 0.375f * (b2 - b1);

            float* op = out + (size_t)(b * NCO + cg) * (OUTW * OUTW) + 4 * k;

            if (r == 0) {                     // rows 0,1: clamped -> pure w-lerp
                f32x4 o = {t0, t1, t2, t3};
                *(f32x4*)(op) = o;
                *(f32x4*)(op + OUTW) = o;
            }
            int nr = (r == 127) ? 2 : 4;
            #pragma unroll
            for (int ri = 0; ri < 4; ++ri) {
                if (ri >= nr) break;          // wave-uniform
                float fh = 0.125f + 0.25f * (float)ri;
                int h = 4 * r + 2 + ri;
                f32x4 o;
                o.x = t0 + fh * (u0 - t0);
                o.y = t1 + fh * (u1 - t1);
                o.z = t2 + fh * (u2 - t2);
                o.w = t3 + fh * (u3 - t3);
                *(f32x4*)(op + (size_t)h * OUTW) = o;
            }
        }
    }
}

extern "C" void kernel_launch(void* const* d_in, const int* in_sizes, int n_in,
                              void* d_out, int out_size, void* d_ws, size_t ws_size,
                              hipStream_t stream) {
    const float* logits = (const float*)d_in[0];
    const float* masks  = (const float*)d_in[1];
    float* out = (float*)d_out;

    fused_k<<<dim3(128, NB), dim3(1024), 0, stream>>>(logits, masks, out);
}